// Round 6
// baseline (1269.975 us; speedup 1.0000x reference)
//
#include <hip/hip_runtime.h>
#include <stdint.h>

// lap = I - adj/k, adj = exact k-NN graph (incl. self) under euclidean
// distance with jax.lax.top_k tie-break (lower index wins).
// One wave per row. Selection = per-lane sorted top-5 cache + ballot-based
// binary search for the kth distance (no serial swizzle chains), membership
// scattered into a per-wave LDS bitmask via ds_or. Exact: saturation
// (lane holding >4 of the top-k) is detected and falls back to a serial
// wave-min extraction (P ~ 9e-4 per row).

constexpr int Npts = 4096;
constexpr int BLK  = 512;   // 8 waves = 8 rows per block

typedef unsigned long long u64;

__device__ inline u64 u64min(u64 a, u64 b) { return a < b ? a : b; }

__device__ inline u64 wave_min64(u64 v) {
#pragma unroll
    for (int off = 1; off < 64; off <<= 1) {
        u64 o = __shfl_xor(v, off, 64);
        v = u64min(v, o);
    }
    return v;
}

__device__ inline unsigned wave_min32(unsigned v) {
#pragma unroll
    for (int off = 1; off < 64; off <<= 1) {
        unsigned o = __shfl_xor(v, off, 64);
        v = v < o ? v : o;
    }
    return v;
}

__device__ inline unsigned wave_max32(unsigned v) {
#pragma unroll
    for (int off = 1; off < 64; off <<= 1) {
        unsigned o = __shfl_xor(v, off, 64);
        v = v > o ? v : o;
    }
    return v;
}

// d2(i, j) with reference rounding (no fma contraction); deterministic ->
// recomputation (fallback path) is bitwise-identical to the scan pass.
__device__ inline float cand_d2(const float4* __restrict__ pts4, unsigned j,
                                float ax, float ay, float az, float sqi) {
    const float4 pj = pts4[j];
    const float dot = __fadd_rn(__fadd_rn(__fmul_rn(ax, pj.x), __fmul_rn(ay, pj.y)),
                                __fmul_rn(az, pj.z));
    const float v = __fsub_rn(__fadd_rn(sqi, pj.w), __fmul_rn(2.0f, dot));
    return fmaxf(v, 0.0f);   // result >= +0.0 -> u32 bit order == float order
}

__global__ __launch_bounds__(BLK, 4) void gcn_lap_kernel(const float* __restrict__ x,
                                                         const int* __restrict__ kptr,
                                                         float* __restrict__ out) {
    __shared__ float4 pts4[Npts];            // 64 KB: (x, y, z, |p|^2)
    __shared__ unsigned wmaskLDS[8 * 128];   // 4 KB: 4096-bit adjacency row / wave

    const int tid  = threadIdx.x;
    const int lane = tid & 63;
    const int wv   = tid >> 6;
    const int b    = blockIdx.x >> 9;                  // 512 blocks per batch
    const int i    = ((blockIdx.x & 511) << 3) | wv;   // this wave's row (0..4095)

    int k = *kptr;
    if (k < 1) k = 1;
    if (k > Npts) k = Npts;

    // ---- stage points once per block: (x,y,z,sq), sq with reference rounding ----
    const float* xb = x + (size_t)b * (Npts * 3);
#pragma unroll
    for (int s = 0; s < Npts / BLK; ++s) {
        const int p = tid + BLK * s;
        const float bx = xb[3 * p], by = xb[3 * p + 1], bz = xb[3 * p + 2];
        const float sq = __fadd_rn(__fadd_rn(__fmul_rn(bx, bx), __fmul_rn(by, by)),
                                   __fmul_rn(bz, bz));
        pts4[p] = make_float4(bx, by, bz, sq);
    }
    __syncthreads();

    const float4 pi = pts4[i];               // wave-uniform broadcast read
    const float ax = pi.x, ay = pi.y, az = pi.z, sqi = pi.w;
    const float INF_F = __uint_as_float(0x7f800000u);

    // ---- scan: per-lane sorted top-5 distances + candidate indices ----
    // strict '<' keeps earlier (lower c -> lower j) first on ties.
    float d0 = INF_F, d1 = INF_F, d2v = INF_F, d3 = INF_F, d4 = INF_F;
    unsigned c0 = 0, c1 = 0, c2 = 0, c3 = 0, c4 = 0;
#pragma unroll
    for (unsigned c = 0; c < 64; ++c) {
        const unsigned j = (c << 6) | (unsigned)lane;   // ds_read imm offset c*1024
        const float d = cand_d2(pts4, j, ax, ay, az, sqi);
        const bool b1 = d < d0, b2 = d < d1, b3 = d < d2v, b4 = d < d3, b5 = d < d4;
        const float n0 = fminf(d0, d);
        const float n1 = __builtin_amdgcn_fmed3f(d0, d1, d);
        const float n2 = __builtin_amdgcn_fmed3f(d1, d2v, d);
        const float n3 = __builtin_amdgcn_fmed3f(d2v, d3, d);
        const float n4 = __builtin_amdgcn_fmed3f(d3, d4, d);
        const unsigned m0 = b1 ? c : c0;
        const unsigned m1 = b1 ? c0 : (b2 ? c : c1);
        const unsigned m2 = b2 ? c1 : (b3 ? c : c2);
        const unsigned m3 = b3 ? c2 : (b4 ? c : c3);
        const unsigned m4 = b4 ? c3 : (b5 ? c : c4);
        d0 = n0; d1 = n1; d2v = n2; d3 = n3; d4 = n4;
        c0 = m0; c1 = m1; c2 = m2; c3 = m3; c4 = m4;
    }
    const unsigned db0 = __float_as_uint(d0), db1 = __float_as_uint(d1),
                   db2 = __float_as_uint(d2v), db3 = __float_as_uint(d3),
                   db4 = __float_as_uint(d4);

    // ---- binary search for D = bits of the kth smallest distance ----
    unsigned lo = wave_min32(db0);           // f(lo) = 0 < k
    unsigned hi = wave_max32(db4) + 1u;      // f(hi) >= 5*64 >= k (k <= 256 guard)
    unsigned n_lt = 0;
    while (hi - lo > 1u) {
        const unsigned mid = (lo + hi) >> 1;
        unsigned cnt = (unsigned)__popcll(__ballot(db0 < mid)) +
                       (unsigned)__popcll(__ballot(db1 < mid)) +
                       (unsigned)__popcll(__ballot(db2 < mid)) +
                       (unsigned)__popcll(__ballot(db3 < mid)) +
                       (unsigned)__popcll(__ballot(db4 < mid));
        if (cnt < (unsigned)k) { lo = mid; n_lt = cnt; } else { hi = mid; }
    }
    // exact unless some lane's 5th-smallest <= D (cache may hide entries < D)
    const bool bad = (__any(db4 <= lo) != 0) || (k > 256);

    // ---- zero this wave's 4096-bit mask (in-order DS pipe per wave) ----
    unsigned* wm = wmaskLDS + wv * 128;
    wm[2 * lane]     = 0u;
    wm[2 * lane + 1] = 0u;

    if (!bad) {
        // all entries with dist < D are cached (not-bad); scatter their bits
        u64 eqmask = 0;
#pragma unroll
        for (int s = 0; s < 5; ++s) {
            const unsigned dbs = (s == 0) ? db0 : (s == 1) ? db1 : (s == 2) ? db2
                                 : (s == 3) ? db3 : db4;
            const unsigned cs  = (s == 0) ? c0 : (s == 1) ? c1 : (s == 2) ? c2
                                 : (s == 3) ? c3 : c4;
            const unsigned j = (cs << 6) | (unsigned)lane;
            if (dbs < lo) atomicOr(&wm[j >> 5], 1u << (j & 31u));
            if (dbs == lo) eqmask |= 1ull << cs;
        }
        // pick (k - n_lt) lowest-j entries among dist == D
        int rem = k - (int)n_lt;
        while (rem > 0) {
            const unsigned myj = eqmask
                ? (((unsigned)(__ffsll((long long)eqmask) - 1) << 6) | (unsigned)lane)
                : 0xFFFFFFFFu;
            const unsigned mn = wave_min32(myj);
            if (mn == 0xFFFFFFFFu) break;    // safety (cannot happen when exact)
            if (myj == mn) {
                eqmask &= eqmask - 1;        // clear lowest set bit
                atomicOr(&wm[mn >> 5], 1u << (mn & 31u));
            }
            --rem;
        }
    } else {
        // ---- exact serial fallback: k rounds of wave-min over rescans ----
        u64 used = 0;
        for (int t = 0; t < k; ++t) {
            u64 best = ~0ull;
#pragma unroll 8
            for (unsigned c = 0; c < 64; ++c) {
                if (!((used >> c) & 1ull)) {
                    const unsigned j = (c << 6) | (unsigned)lane;
                    const float d = cand_d2(pts4, j, ax, ay, az, sqi);
                    best = u64min(best, ((u64)__float_as_uint(d) << 32) | j);
                }
            }
            const u64 m = wave_min64(best);
            if (m == ~0ull) break;
            if (best == m) {                 // unique low bits -> one winner lane
                const unsigned j = (unsigned)m;
                used |= 1ull << (j >> 6);
                atomicOr(&wm[j >> 5], 1u << (j & 31u));
            }
        }
    }

    // drain this wave's ds_or traffic before reading the mask back
    asm volatile("s_waitcnt lgkmcnt(0)" ::: "memory");

    // ---- emit row from LDS bitmask: coalesced float4 stream ----
    const float r = 1.0f / sqrtf((float)k);
    const float negrr = -__fmul_rn(r, r);    // -(dinv_i*dinv_j); deg == k exactly
    float4* o4 = (float4*)(out + (size_t)(b * Npts + i) * Npts);
    const unsigned sh = ((unsigned)lane & 7u) << 2;   // nibble shift in dword
    const int qi = i >> 8;                            // uniform: q holding the diag
#pragma unroll
    for (int q = 0; q < 16; ++q) {
        const unsigned word = wm[(q << 3) | (lane >> 3)];  // 8-lane broadcast
        const unsigned nib = (word >> sh) & 0xFu;
        float4 v;
        v.x = (nib & 1u) ? negrr : 0.0f;
        v.y = (nib & 2u) ? negrr : 0.0f;
        v.z = (nib & 4u) ? negrr : 0.0f;
        v.w = (nib & 8u) ? negrr : 0.0f;
        if (q == qi) {                        // uniform branch: diag lives here
            const int j0 = (q << 8) | (lane << 2);
            v.x = __fadd_rn(v.x, (j0 + 0 == i) ? 1.0f : 0.0f);
            v.y = __fadd_rn(v.y, (j0 + 1 == i) ? 1.0f : 0.0f);
            v.z = __fadd_rn(v.z, (j0 + 2 == i) ? 1.0f : 0.0f);
            v.w = __fadd_rn(v.w, (j0 + 3 == i) ? 1.0f : 0.0f);
        }
        o4[(q << 6) | lane] = v;
    }
}

extern "C" void kernel_launch(void* const* d_in, const int* in_sizes, int n_in,
                              void* d_out, int out_size, void* d_ws, size_t ws_size,
                              hipStream_t stream) {
    const float* x    = (const float*)d_in[0];
    const int*   kptr = (const int*)d_in[1];
    float*       out  = (float*)d_out;
    const int B = in_sizes[0] / (Npts * 3);
    hipLaunchKernelGGL(gcn_lap_kernel, dim3(B * 512), dim3(BLK), 0, stream,
                       x, kptr, out);
}

// Round 7
// 179.816 us; speedup vs baseline: 7.0626x; 7.0626x over previous
//
#include <hip/hip_runtime.h>
#include <stdint.h>

// lap = I - adj/k, adj = exact k-NN graph (incl. self) under euclidean
// distance with jax.lax.top_k tie-break (lower index wins).
// One wave per row. Selection:
//   pass1: per-lane sorted top-5 DISTANCES (fmin/med3, no indices -> tiny
//          register pressure; R5 spilled 3.4GB of scratch tracking indices)
//   ballot binary search over float-bit space for D = kth smallest
//   pass2: recompute d (bitwise-identical), ds_or `< D` bits into per-wave
//          LDS bitmask; lowest-j rounds for the == D remainder.
// Exact: if any lane's 5th-smallest <= D the cache may hide entries -> serial
// fallback (P ~ 9e-4 per row).

constexpr int Npts = 4096;
constexpr int BLK  = 512;   // 8 waves = 8 rows per block

typedef unsigned long long u64;

__device__ inline u64 u64min(u64 a, u64 b) { return a < b ? a : b; }

__device__ inline u64 wave_min64(u64 v) {
#pragma unroll
    for (int off = 1; off < 64; off <<= 1) {
        u64 o = __shfl_xor(v, off, 64);
        v = u64min(v, o);
    }
    return v;
}

__device__ inline unsigned wave_min32(unsigned v) {
#pragma unroll
    for (int off = 1; off < 64; off <<= 1) {
        unsigned o = __shfl_xor(v, off, 64);
        v = v < o ? v : o;
    }
    return v;
}

// d2(i, j) with reference rounding (no fma contraction); deterministic ->
// pass2 / fallback recomputation is bitwise-identical to pass1.
__device__ inline float cand_d2(const float4* __restrict__ pts4, unsigned j,
                                float ax, float ay, float az, float sqi) {
    const float4 pj = pts4[j];
    const float dot = __fadd_rn(__fadd_rn(__fmul_rn(ax, pj.x), __fmul_rn(ay, pj.y)),
                                __fmul_rn(az, pj.z));
    const float v = __fsub_rn(__fadd_rn(sqi, pj.w), __fmul_rn(2.0f, dot));
    return fmaxf(v, 0.0f);   // >= +0.0 -> u32 bit order == float order
}

__global__ __launch_bounds__(BLK, 2) void gcn_lap_kernel(const float* __restrict__ x,
                                                         const int* __restrict__ kptr,
                                                         float* __restrict__ out) {
    __shared__ float4 pts4[Npts];            // 64 KB: (x, y, z, |p|^2)
    __shared__ unsigned wmaskLDS[8 * 128];   // 4 KB: 4096-bit adjacency row / wave

    const int tid  = threadIdx.x;
    const int lane = tid & 63;
    const int wv   = tid >> 6;
    const int b    = blockIdx.x >> 9;                  // 512 blocks per batch
    const int i    = ((blockIdx.x & 511) << 3) | wv;   // this wave's row (0..4095)

    int k = *kptr;
    if (k < 1) k = 1;
    if (k > Npts) k = Npts;

    // ---- stage points once per block: (x,y,z,sq), sq with reference rounding ----
    const float* xb = x + (size_t)b * (Npts * 3);
#pragma unroll
    for (int s = 0; s < Npts / BLK; ++s) {
        const int p = tid + BLK * s;
        const float bx = xb[3 * p], by = xb[3 * p + 1], bz = xb[3 * p + 2];
        const float sq = __fadd_rn(__fadd_rn(__fmul_rn(bx, bx), __fmul_rn(by, by)),
                                   __fmul_rn(bz, bz));
        pts4[p] = make_float4(bx, by, bz, sq);
    }
    __syncthreads();

    const float4 pi = pts4[i];               // wave-uniform broadcast read
    const float ax = pi.x, ay = pi.y, az = pi.z, sqi = pi.w;
    const float INF_F = __uint_as_float(0x7f800000u);

    // ---- pass1: per-lane sorted top-5 distances (NO indices) ----
    float d0 = INF_F, d1 = INF_F, d2v = INF_F, d3 = INF_F, d4 = INF_F;
#pragma unroll 8
    for (unsigned c = 0; c < 64; ++c) {
        const unsigned j = (c << 6) | (unsigned)lane;   // strided: conflict-free
        const float d = cand_d2(pts4, j, ax, ay, az, sqi);
        const float n4 = __builtin_amdgcn_fmed3f(d3, d4, d);  // all use OLD values
        const float n3 = __builtin_amdgcn_fmed3f(d2v, d3, d);
        const float n2 = __builtin_amdgcn_fmed3f(d1, d2v, d);
        const float n1 = __builtin_amdgcn_fmed3f(d0, d1, d);
        const float n0 = fminf(d0, d);
        d0 = n0; d1 = n1; d2v = n2; d3 = n3; d4 = n4;
    }
    const unsigned db0 = __float_as_uint(d0), db1 = __float_as_uint(d1),
                   db2 = __float_as_uint(d2v), db3 = __float_as_uint(d3),
                   db4 = __float_as_uint(d4);

    // ---- ballot binary search for D = bits of the kth smallest distance ----
    unsigned lo = 0u;                 // f(0) = 0 < k
    unsigned hi = 0x7f800001u;        // counts everything (<= +inf)
    unsigned n_lt = 0;
    while (hi - lo > 1u) {
        const unsigned mid = (lo + hi) >> 1;
        const unsigned cnt = (unsigned)__popcll(__ballot(db0 < mid)) +
                             (unsigned)__popcll(__ballot(db1 < mid)) +
                             (unsigned)__popcll(__ballot(db2 < mid)) +
                             (unsigned)__popcll(__ballot(db3 < mid)) +
                             (unsigned)__popcll(__ballot(db4 < mid));
        if (cnt < (unsigned)k) { lo = mid; n_lt = cnt; } else { hi = mid; }
    }
    // exact unless some lane's cache might hide entries <= D
    const bool bad = (__any(db4 <= lo) != 0) || (k > 256);

    // ---- zero this wave's 4096-bit mask ----
    unsigned* wm = wmaskLDS + wv * 128;
    wm[2 * lane]     = 0u;
    wm[2 * lane + 1] = 0u;

    if (!bad) {
        // ---- pass2: recompute, scatter `< D`, collect `== D` ----
        u64 eqmask = 0;
#pragma unroll 8
        for (unsigned c = 0; c < 64; ++c) {
            const unsigned j = (c << 6) | (unsigned)lane;
            const float d = cand_d2(pts4, j, ax, ay, az, sqi);
            const unsigned dbits = __float_as_uint(d);
            if (dbits < lo) atomicOr(&wmaskLDS[wv * 128 + (j >> 5)], 1u << (j & 31u));
            if (dbits == lo) eqmask |= 1ull << c;
        }
        // pick (k - n_lt) lowest-j entries among dist == D (typically 1 round)
        int rem = k - (int)n_lt;
        while (rem > 0) {
            const unsigned myj = eqmask
                ? (((unsigned)(__ffsll((long long)eqmask) - 1) << 6) | (unsigned)lane)
                : 0xFFFFFFFFu;
            const unsigned mn = wave_min32(myj);
            if (mn == 0xFFFFFFFFu) break;    // safety (cannot happen when !bad)
            if (myj == mn) {
                eqmask &= eqmask - 1;        // clear lowest set bit
                atomicOr(&wmaskLDS[wv * 128 + (mn >> 5)], 1u << (mn & 31u));
            }
            --rem;
        }
    } else {
        // ---- exact serial fallback: k rounds of wave-min over rescans ----
        u64 used = 0;
        for (int t = 0; t < k; ++t) {
            u64 best = ~0ull;
#pragma unroll 8
            for (unsigned c = 0; c < 64; ++c) {
                if (!((used >> c) & 1ull)) {
                    const unsigned j = (c << 6) | (unsigned)lane;
                    const float d = cand_d2(pts4, j, ax, ay, az, sqi);
                    best = u64min(best, ((u64)__float_as_uint(d) << 32) | j);
                }
            }
            const u64 m = wave_min64(best);
            if (m == ~0ull) break;
            if (best == m) {                 // unique low bits -> one winner lane
                const unsigned j = (unsigned)m;
                used |= 1ull << (j >> 6);
                atomicOr(&wmaskLDS[wv * 128 + (j >> 5)], 1u << (j & 31u));
            }
        }
    }

    // ---- emit row from LDS bitmask: coalesced float4 stream ----
    // (same-wave DS ops complete in order; compiler orders the reads after the
    //  atomics since they may alias)
    const float r = 1.0f / sqrtf((float)k);
    const float negrr = -__fmul_rn(r, r);    // -(dinv_i*dinv_j); deg == k exactly
    float4* o4 = (float4*)(out + (size_t)(b * Npts + i) * Npts);
    const unsigned sh = ((unsigned)lane & 7u) << 2;   // nibble shift in dword
    const int qi = i >> 8;                            // uniform: q holding the diag
#pragma unroll
    for (int q = 0; q < 16; ++q) {
        const unsigned word = wm[(q << 3) | (lane >> 3)];  // 8-lane broadcast
        const unsigned nib = (word >> sh) & 0xFu;
        float4 v;
        v.x = (nib & 1u) ? negrr : 0.0f;
        v.y = (nib & 2u) ? negrr : 0.0f;
        v.z = (nib & 4u) ? negrr : 0.0f;
        v.w = (nib & 8u) ? negrr : 0.0f;
        if (q == qi) {                        // uniform branch: diag lives here
            const int j0 = (q << 8) | (lane << 2);
            v.x = __fadd_rn(v.x, (j0 + 0 == i) ? 1.0f : 0.0f);
            v.y = __fadd_rn(v.y, (j0 + 1 == i) ? 1.0f : 0.0f);
            v.z = __fadd_rn(v.z, (j0 + 2 == i) ? 1.0f : 0.0f);
            v.w = __fadd_rn(v.w, (j0 + 3 == i) ? 1.0f : 0.0f);
        }
        o4[(q << 6) | lane] = v;
    }
}

extern "C" void kernel_launch(void* const* d_in, const int* in_sizes, int n_in,
                              void* d_out, int out_size, void* d_ws, size_t ws_size,
                              hipStream_t stream) {
    const float* x    = (const float*)d_in[0];
    const int*   kptr = (const int*)d_in[1];
    float*       out  = (float*)d_out;
    const int B = in_sizes[0] / (Npts * 3);
    hipLaunchKernelGGL(gcn_lap_kernel, dim3(B * 512), dim3(BLK), 0, stream,
                       x, kptr, out);
}